// Round 1
// baseline (2646.071 us; speedup 1.0000x reference)
//
#include <hip/hip_runtime.h>
#include <math.h>

// NUFFT roundtrip: out[bc,x,y] = sum_m conj(Ax[m,x]) conj(Ay[m,y]) ksp[bc,m]
//                  ksp[bc,m]   = sum_{x,y} Ax[m,x] Ay[m,y] img[bc,x,y]
// A*[m,g] = exp(-2*pi*i * k_m * (g - N/2) / N), computed on the fly via __sincosf.
// fp32 VALU baseline (no fp32 MFMA on CDNA4). Deterministic: no atomics.

#define NN   320
#define BCC  8
#define TM   64
#define TN   64
#define TK   16
#define NYT  5          // NN / TN
#define SK   4          // split-K chunks for adjoint
#define CW   0.019634954084936207f   // 2*pi/NN

__device__ __forceinline__ float gval(int i) { return (float)(i - NN/2); }

// ---------------- forward: partial1[bc][yt][m] = sum_{y in tile} t[m,y]*Ay[m,y]
__global__ __launch_bounds__(256) void fwd_kernel(
    const float* __restrict__ inp, const float* __restrict__ traj,
    float2* __restrict__ partial1, int M)
{
    __shared__ float2 lds_a[TK][TM];   // Ax[x=k][m=c]
    __shared__ float2 lds_b[TK][TN];   // img[x=k][y=c]
    __shared__ float  lds_kx[TM];
    __shared__ float  lds_ky[TM];

    const int tid = threadIdx.x;
    const int tx  = tid & 15;
    const int ty  = tid >> 4;
    const int m0  = blockIdx.x * TM;
    const int y0  = blockIdx.y * TN;
    const int bc  = blockIdx.z;

    if (tid < TM) {
        int mg = m0 + tid;
        lds_kx[tid] = (mg < M) ? traj[2*mg]     : 0.f;
        lds_ky[tid] = (mg < M) ? traj[2*mg + 1] : 0.f;
    }
    __syncthreads();

    float2 acc[4][4];
    #pragma unroll
    for (int i = 0; i < 4; ++i)
        #pragma unroll
        for (int j = 0; j < 4; ++j) acc[i][j] = make_float2(0.f, 0.f);

    const float2* imgp = (const float2*)inp;   // (bc, x, y)

    for (int x0 = 0; x0 < NN; x0 += TK) {
        // A tile: Ax[m, x] = exp(-i * CW * kx[m] * g(x))
        #pragma unroll
        for (int it = 0; it < 4; ++it) {
            int i = tid + it * 256;
            int k = i >> 6, c = i & 63;
            float th = CW * lds_kx[c] * gval(x0 + k);
            float s, cs;
            __sincosf(th, &s, &cs);
            lds_a[k][c] = make_float2(cs, -s);
        }
        // B tile: img[bc, x, y]
        #pragma unroll
        for (int it = 0; it < 4; ++it) {
            int i = tid + it * 256;
            int k = i >> 6, c = i & 63;
            lds_b[k][c] = imgp[((size_t)bc * NN + (x0 + k)) * NN + (y0 + c)];
        }
        __syncthreads();

        #pragma unroll
        for (int k = 0; k < TK; ++k) {
            float2 a[4], b[4];
            #pragma unroll
            for (int i = 0; i < 4; ++i) a[i] = lds_a[k][ty*4 + i];
            #pragma unroll
            for (int j = 0; j < 4; ++j) b[j] = lds_b[k][tx*4 + j];
            #pragma unroll
            for (int i = 0; i < 4; ++i)
                #pragma unroll
                for (int j = 0; j < 4; ++j) {
                    acc[i][j].x += a[i].x*b[j].x - a[i].y*b[j].y;
                    acc[i][j].y += a[i].x*b[j].y + a[i].y*b[j].x;
                }
        }
        __syncthreads();
    }

    // epilogue: s_i = sum_j acc[i][j] * Ay[m_i, y_j],  Ay = cos - i sin
    float2 s[4];
    #pragma unroll
    for (int i = 0; i < 4; ++i) {
        s[i] = make_float2(0.f, 0.f);
        float ky = lds_ky[ty*4 + i];
        #pragma unroll
        for (int j = 0; j < 4; ++j) {
            float th = CW * ky * gval(y0 + tx*4 + j);
            float sn, cs;
            __sincosf(th, &sn, &cs);
            float2 t = acc[i][j];
            s[i].x += t.x*cs + t.y*sn;
            s[i].y += t.y*cs - t.x*sn;
        }
    }
    // reduce across the 16 tx lanes (lanes sharing lane>>4)
    #pragma unroll
    for (int i = 0; i < 4; ++i) {
        #pragma unroll
        for (int msk = 8; msk >= 1; msk >>= 1) {
            s[i].x += __shfl_xor(s[i].x, msk);
            s[i].y += __shfl_xor(s[i].y, msk);
        }
    }
    if (tx == 0) {
        #pragma unroll
        for (int i = 0; i < 4; ++i) {
            int m = m0 + ty*4 + i;
            if (m < M)
                partial1[((size_t)(bc * NYT + blockIdx.y)) * M + m] = s[i];
        }
    }
}

// ---------------- reduce partial1 -> ksp
__global__ void reduce_ksp(const float2* __restrict__ partial1,
                           float2* __restrict__ ksp, int M)
{
    int idx = blockIdx.x * 256 + threadIdx.x;   // over BCC*M
    if (idx >= BCC * M) return;
    int bc = idx / M, m = idx - bc * M;
    float2 r = make_float2(0.f, 0.f);
    #pragma unroll
    for (int yt = 0; yt < NYT; ++yt) {
        float2 v = partial1[((size_t)(bc * NYT + yt)) * M + m];
        r.x += v.x; r.y += v.y;
    }
    ksp[idx] = r;
}

// ---------------- adjoint: partial2[sk][bc][x][y] = sum_{m in chunk} conjAx * (ksp*conjAy)
__global__ __launch_bounds__(256) void adj_kernel(
    const float* __restrict__ traj, const float2* __restrict__ ksp,
    float2* __restrict__ partial2, int M)
{
    __shared__ float2 lds_a[TK][TM];   // conj(Ax)[m=k][x=c]
    __shared__ float2 lds_b[TK][TN];   // u[m=k][y=c]

    const int tid = threadIdx.x;
    const int tx  = tid & 15;
    const int ty  = tid >> 4;
    const int x0  = blockIdx.x * TM;
    const int ct  = blockIdx.y;        // bc*NYT + yt
    const int bc  = ct / NYT;
    const int y0  = (ct - bc * NYT) * TN;
    const int sk  = blockIdx.z;
    const int kchunk = (M + SK - 1) / SK;
    const int kbeg = sk * kchunk;
    const int kend = min(kbeg + kchunk, M);

    float2 acc[4][4];
    #pragma unroll
    for (int i = 0; i < 4; ++i)
        #pragma unroll
        for (int j = 0; j < 4; ++j) acc[i][j] = make_float2(0.f, 0.f);

    for (int k0 = kbeg; k0 < kend; k0 += TK) {
        #pragma unroll
        for (int it = 0; it < 4; ++it) {
            int i = tid + it * 256;
            int k = i >> 6, c = i & 63;
            int m = k0 + k;
            float2 v = make_float2(0.f, 0.f);
            if (m < kend) {
                float th = CW * traj[2*m] * gval(x0 + c);
                float s, cs;
                __sincosf(th, &s, &cs);
                v = make_float2(cs, s);            // conj(Ax) = cos + i sin
            }
            lds_a[k][c] = v;
        }
        #pragma unroll
        for (int it = 0; it < 4; ++it) {
            int i = tid + it * 256;
            int k = i >> 6, c = i & 63;
            int m = k0 + k;
            float2 v = make_float2(0.f, 0.f);
            if (m < kend) {
                float th = CW * traj[2*m + 1] * gval(y0 + c);
                float s, cs;
                __sincosf(th, &s, &cs);
                float2 kv = ksp[(size_t)bc * M + m];
                v.x = kv.x*cs - kv.y*s;            // ksp * conj(Ay)
                v.y = kv.x*s  + kv.y*cs;
            }
            lds_b[k][c] = v;
        }
        __syncthreads();

        #pragma unroll
        for (int k = 0; k < TK; ++k) {
            float2 a[4], b[4];
            #pragma unroll
            for (int i = 0; i < 4; ++i) a[i] = lds_a[k][ty*4 + i];
            #pragma unroll
            for (int j = 0; j < 4; ++j) b[j] = lds_b[k][tx*4 + j];
            #pragma unroll
            for (int i = 0; i < 4; ++i)
                #pragma unroll
                for (int j = 0; j < 4; ++j) {
                    acc[i][j].x += a[i].x*b[j].x - a[i].y*b[j].y;
                    acc[i][j].y += a[i].x*b[j].y + a[i].y*b[j].x;
                }
        }
        __syncthreads();
    }

    #pragma unroll
    for (int i = 0; i < 4; ++i)
        #pragma unroll
        for (int j = 0; j < 4; ++j) {
            int x = x0 + ty*4 + i;
            int y = y0 + tx*4 + j;
            partial2[(((size_t)sk * BCC + bc) * NN + x) * NN + y] = acc[i][j];
        }
}

// ---------------- reduce partial2 -> out
__global__ void reduce_out(const float2* __restrict__ partial2,
                           float2* __restrict__ out)
{
    size_t total = (size_t)BCC * NN * NN;
    size_t idx = (size_t)blockIdx.x * 256 + threadIdx.x;
    if (idx >= total) return;
    float2 r = make_float2(0.f, 0.f);
    #pragma unroll
    for (int s = 0; s < SK; ++s) {
        float2 v = partial2[s * total + idx];
        r.x += v.x; r.y += v.y;
    }
    out[idx] = r;
}

extern "C" void kernel_launch(void* const* d_in, const int* in_sizes, int n_in,
                              void* d_out, int out_size, void* d_ws, size_t ws_size,
                              hipStream_t stream)
{
    const float* inp  = (const float*)d_in[0];
    const float* traj = (const float*)d_in[1];
    const int M = in_sizes[1] / 2;    // 6008

    // workspace layout (all 256B-aligned)
    char* ws = (char*)d_ws;
    size_t off = 0;
    float2* ksp = (float2*)(ws + off);
    off += ((size_t)BCC * M * sizeof(float2) + 255) & ~(size_t)255;
    float2* partial1 = (float2*)(ws + off);
    off += ((size_t)BCC * NYT * M * sizeof(float2) + 255) & ~(size_t)255;
    float2* partial2 = (float2*)(ws + off);
    // off += SK * BCC * NN * NN * 8  (~26 MB) — total ~28.5 MB required

    dim3 g1((M + TM - 1) / TM, NYT, BCC);
    fwd_kernel<<<g1, 256, 0, stream>>>(inp, traj, partial1, M);

    reduce_ksp<<<(BCC * M + 255) / 256, 256, 0, stream>>>(partial1, ksp, M);

    dim3 g3(NN / TM, BCC * NYT, SK);
    adj_kernel<<<g3, 256, 0, stream>>>(traj, ksp, partial2, M);

    size_t total = (size_t)BCC * NN * NN;
    reduce_out<<<(int)((total + 255) / 256), 256, 0, stream>>>(partial2, (float2*)d_out);
}

// Round 2
// 297.759 us; speedup vs baseline: 8.8866x; 8.8866x over previous
//
#include <hip/hip_runtime.h>
#include <math.h>

// NUFFT roundtrip on bf16 MFMA (16x16x32), fp32 accumulate.
// fwd:  D[y][m] = sum_x imgT[y][x] * Ax[m][x]   (A=imgT, B=Ax as Bt[c=m][k=x])
//       ksp[m]  = sum_y D[y][m] * Ay[m][y]      (fused epilogue, Ay=(c,-s))
// adj:  out[x][y] += sum_m W[x][m] * conjAy[m][y],  W = conjAx^T * diag(ksp)
// Planes: Ax[m][x]=(c,-s), AxTc[x][m]=(c,+s), AyT[y][m]=(c,+s) all bf16.

#define NN      320
#define BCC     8
#define MREAL   6008
#define MSTR    6144          // padded m stride (all [..][m] planes), 96*64
#define MT1     47            // fwd m-tiles of 128 -> 6016 cols
#define P1STR   6016
#define NCHUNK  4
#define CHUNK   1536          // 4*1536 = 6144
#define TWOPI   6.283185307179586f

typedef __attribute__((ext_vector_type(8))) short short8_t;
typedef __attribute__((ext_vector_type(4))) float float4_t;

__device__ __forceinline__ unsigned short f2bf(float f) {
    union { float f; unsigned u; } v; v.f = f;
    unsigned r = v.u + 0x7fff + ((v.u >> 16) & 1);
    return (unsigned short)(r >> 16);
}
__device__ __forceinline__ float bf2f(unsigned short h) {
    union { unsigned u; float f; } v; v.u = ((unsigned)h) << 16;
    return v.f;
}
__device__ __forceinline__ short8_t neg8(short8_t v) {
    short8_t r;
    #pragma unroll
    for (int i = 0; i < 8; ++i) r[i] = v[i] ^ (short)0x8000;
    return r;
}
__device__ __forceinline__ float gval(int i) { return (float)(i - NN/2); }

// phase in revolutions -> accurate reduced sincos of exp(-2pi*i*k*g/NN)
__device__ __forceinline__ void phase_cs(float k, float g, float* c, float* s) {
    float rev = k * (g * (1.0f / (float)NN));
    rev -= rintf(rev);
    float th = rev * TWOPI;
    __sincosf(th, s, c);
}

// ============ gen_A: build Ax[m][x], AxTc[x][m], AyT[y][m] ============
__global__ __launch_bounds__(256) void gen_A(
    const float* __restrict__ traj,
    unsigned short* __restrict__ Ax_r, unsigned short* __restrict__ Ax_i,
    unsigned short* __restrict__ AxT_r, unsigned short* __restrict__ AxT_i,
    unsigned short* __restrict__ AyT_r, unsigned short* __restrict__ AyT_i)
{
    __shared__ __align__(16) float lc[64][65];
    __shared__ __align__(16) float ls[64][65];
    __shared__ float kxv[64], kyv[64];
    const int tid = threadIdx.x;
    const int m0 = blockIdx.x * 64;
    const int g0 = blockIdx.y * 64;

    if (tid < 64) {
        int m = m0 + tid;
        kxv[tid] = (m < MREAL) ? traj[2*m]     : 0.f;
        kyv[tid] = (m < MREAL) ? traj[2*m + 1] : 0.f;
    }
    __syncthreads();

    // ---- phase 1: x planes ----
    #pragma unroll
    for (int it = 0; it < 16; ++it) {
        int e = tid + it * 256;
        int mi = e >> 6, gi = e & 63;
        float c, s;
        phase_cs(kxv[mi], gval(g0 + gi), &c, &s);
        bool valid = (m0 + mi) < MREAL;
        lc[mi][gi] = valid ? c : 0.f;
        ls[mi][gi] = valid ? s : 0.f;
    }
    __syncthreads();
    #pragma unroll
    for (int it = 0; it < 16; ++it) {       // Ax[m][x] = (c, -s)
        int e = tid + it * 256;
        int mi = e >> 6, xi = e & 63;
        size_t o = (size_t)(m0 + mi) * NN + (g0 + xi);
        Ax_r[o] = f2bf(lc[mi][xi]);
        Ax_i[o] = f2bf(-ls[mi][xi]);
    }
    #pragma unroll
    for (int it = 0; it < 16; ++it) {       // AxTc[x][m] = (c, +s)
        int e = tid + it * 256;
        int xi = e >> 6, mi = e & 63;
        size_t o = (size_t)(g0 + xi) * MSTR + (m0 + mi);
        AxT_r[o] = f2bf(lc[mi][xi]);
        AxT_i[o] = f2bf(ls[mi][xi]);
    }
    __syncthreads();

    // ---- phase 2: y plane (transposed only) ----
    #pragma unroll
    for (int it = 0; it < 16; ++it) {
        int e = tid + it * 256;
        int mi = e >> 6, gi = e & 63;
        float c, s;
        phase_cs(kyv[mi], gval(g0 + gi), &c, &s);
        bool valid = (m0 + mi) < MREAL;
        lc[mi][gi] = valid ? c : 0.f;
        ls[mi][gi] = valid ? s : 0.f;
    }
    __syncthreads();
    #pragma unroll
    for (int it = 0; it < 16; ++it) {       // AyT[y][m] = (c, +s)  (conj-ready)
        int e = tid + it * 256;
        int yi = e >> 6, mi = e & 63;
        size_t o = (size_t)(g0 + yi) * MSTR + (m0 + mi);
        AyT_r[o] = f2bf(lc[mi][yi]);
        AyT_i[o] = f2bf(ls[mi][yi]);
    }
}

// ============ conv_img: inp float2 [bc][x][y] -> imgT bf16 [bc][y][x] ============
__global__ __launch_bounds__(256) void conv_img(
    const float* __restrict__ inp,
    unsigned short* __restrict__ iT_r, unsigned short* __restrict__ iT_i)
{
    __shared__ __align__(16) float2 t[64][65];
    const int tid = threadIdx.x;
    const int x0 = blockIdx.x * 64, y0 = blockIdx.y * 64, bc = blockIdx.z;
    const float2* ip = (const float2*)inp;
    #pragma unroll
    for (int it = 0; it < 16; ++it) {
        int e = tid + it * 256;
        int r = e >> 6, c = e & 63;
        t[r][c] = ip[((size_t)bc * NN + (x0 + r)) * NN + (y0 + c)];
    }
    __syncthreads();
    #pragma unroll
    for (int it = 0; it < 16; ++it) {
        int e = tid + it * 256;
        int yy = e >> 6, xx = e & 63;
        float2 v = t[xx][yy];
        size_t o = ((size_t)bc * NN + (y0 + yy)) * NN + (x0 + xx);
        iT_r[o] = f2bf(v.x);
        iT_i[o] = f2bf(v.y);
    }
}

// ============ fwd_gemm: 64y x 128m tile, BK=32, fused Ay-reduce ============
__global__ __launch_bounds__(256) void fwd_gemm(
    const unsigned short* __restrict__ iT_r, const unsigned short* __restrict__ iT_i,
    const unsigned short* __restrict__ Ax_r, const unsigned short* __restrict__ Ax_i,
    const unsigned short* __restrict__ AyT_r, const unsigned short* __restrict__ AyT_i,
    float2* __restrict__ partial1)
{
    __shared__ __align__(16) unsigned short Ar[64][40],  Ai[64][40];
    __shared__ __align__(16) unsigned short Br[128][40], Bi[128][40];
    __shared__ __align__(16) float2 redbuf[2][128];

    const int tid = threadIdx.x;
    const int m0 = blockIdx.x * 128;
    const int y0 = blockIdx.y * 64;
    const int bc = blockIdx.z;

    float4_t accR[2][4], accI[2][4];
    #pragma unroll
    for (int i = 0; i < 2; ++i)
        #pragma unroll
        for (int j = 0; j < 4; ++j) { accR[i][j] = (float4_t)0.f; accI[i][j] = (float4_t)0.f; }

    const int lane = tid & 63, wid = tid >> 6;
    const int wy = wid & 1, wm = wid >> 1;
    const int ar = lane & 15, kb = lane >> 4;

    const int srow = tid >> 2, skg = tid & 3;

    for (int x0 = 0; x0 < NN; x0 += 32) {
        // stage A (imgT): 64 rows x 32k, re+im
        {
            size_t o = ((size_t)bc * NN + (y0 + srow)) * NN + x0 + skg * 8;
            *(short8_t*)&Ar[srow][skg * 8] = *(const short8_t*)(iT_r + o);
            *(short8_t*)&Ai[srow][skg * 8] = *(const short8_t*)(iT_i + o);
        }
        // stage B (Ax): 128 rows x 32k
        #pragma unroll
        for (int it = 0; it < 2; ++it) {
            int idx = tid + it * 256;
            int row = idx >> 2, kg = idx & 3;
            size_t o = (size_t)(m0 + row) * NN + x0 + kg * 8;
            *(short8_t*)&Br[row][kg * 8] = *(const short8_t*)(Ax_r + o);
            *(short8_t*)&Bi[row][kg * 8] = *(const short8_t*)(Ax_i + o);
        }
        __syncthreads();

        short8_t a_r[2], a_i[2], b_r[4], b_i[4], b_n[4];
        #pragma unroll
        for (int iy = 0; iy < 2; ++iy) {
            int r = wy * 32 + iy * 16 + ar;
            a_r[iy] = *(const short8_t*)&Ar[r][kb * 8];
            a_i[iy] = *(const short8_t*)&Ai[r][kb * 8];
        }
        #pragma unroll
        for (int jm = 0; jm < 4; ++jm) {
            int c = wm * 64 + jm * 16 + ar;
            b_r[jm] = *(const short8_t*)&Br[c][kb * 8];
            b_i[jm] = *(const short8_t*)&Bi[c][kb * 8];
            b_n[jm] = neg8(b_i[jm]);
        }
        #pragma unroll
        for (int iy = 0; iy < 2; ++iy)
            #pragma unroll
            for (int jm = 0; jm < 4; ++jm) {
                accR[iy][jm] = __builtin_amdgcn_mfma_f32_16x16x32_bf16(a_r[iy], b_r[jm], accR[iy][jm], 0, 0, 0);
                accR[iy][jm] = __builtin_amdgcn_mfma_f32_16x16x32_bf16(a_i[iy], b_n[jm], accR[iy][jm], 0, 0, 0);
                accI[iy][jm] = __builtin_amdgcn_mfma_f32_16x16x32_bf16(a_r[iy], b_i[jm], accI[iy][jm], 0, 0, 0);
                accI[iy][jm] = __builtin_amdgcn_mfma_f32_16x16x32_bf16(a_i[iy], b_r[jm], accI[iy][jm], 0, 0, 0);
            }
        __syncthreads();
    }

    // epilogue: ksp partial = sum_y D[y][m]*Ay[m][y], Ay=(c,-s), stored ayi=+s
    #pragma unroll
    for (int jm = 0; jm < 4; ++jm) {
        float sr = 0.f, si = 0.f;
        int m = m0 + wm * 64 + jm * 16 + ar;
        #pragma unroll
        for (int iy = 0; iy < 2; ++iy)
            #pragma unroll
            for (int q = 0; q < 4; ++q) {
                int y = y0 + wy * 32 + iy * 16 + kb * 4 + q;
                float c  = bf2f(AyT_r[(size_t)y * MSTR + m]);
                float sy = bf2f(AyT_i[(size_t)y * MSTR + m]);
                float Tr = accR[iy][jm][q], Ti = accI[iy][jm][q];
                sr += Tr * c + Ti * sy;
                si += Ti * c - Tr * sy;
            }
        sr += __shfl_xor(sr, 16); sr += __shfl_xor(sr, 32);
        si += __shfl_xor(si, 16); si += __shfl_xor(si, 32);
        if ((lane & 48) == 0)
            redbuf[wy][wm * 64 + jm * 16 + ar] = make_float2(sr, si);
    }
    __syncthreads();
    if (tid < 128) {
        float2 a = redbuf[0][tid], b = redbuf[1][tid];
        int m = m0 + tid;
        if (m < MREAL)
            partial1[((size_t)bc * 5 + blockIdx.y) * P1STR + m] = make_float2(a.x + b.x, a.y + b.y);
    }
}

// ============ reduce_ksp ============
__global__ void reduce_ksp(const float2* __restrict__ partial1,
                           float2* __restrict__ ksp)
{
    int mp = blockIdx.x * 256 + threadIdx.x;   // grid (24, 8): 24*256 = 6144
    int bc = blockIdx.y;
    float2 r = make_float2(0.f, 0.f);
    if (mp < MREAL) {
        #pragma unroll
        for (int yt = 0; yt < 5; ++yt) {
            float2 v = partial1[((size_t)bc * 5 + yt) * P1STR + mp];
            r.x += v.x; r.y += v.y;
        }
    }
    ksp[(size_t)bc * MSTR + mp] = r;
}

// ============ gen_W: W[bc][x][mloc] = AxTc[x][m] * ksp[bc][m] ============
__global__ void gen_W(const unsigned short* __restrict__ AxT_r,
                      const unsigned short* __restrict__ AxT_i,
                      const float2* __restrict__ ksp,
                      unsigned short* __restrict__ W_r,
                      unsigned short* __restrict__ W_i, int kbeg)
{
    int mloc = blockIdx.x * 256 + threadIdx.x;   // grid (6, 320, 8): 6*256 = 1536
    int x = blockIdx.y, bc = blockIdx.z;
    int m = kbeg + mloc;
    float axr = bf2f(AxT_r[(size_t)x * MSTR + m]);
    float axi = bf2f(AxT_i[(size_t)x * MSTR + m]);
    float2 k = ksp[(size_t)bc * MSTR + m];
    size_t o = ((size_t)bc * NN + x) * CHUNK + mloc;
    W_r[o] = f2bf(axr * k.x - axi * k.y);
    W_i[o] = f2bf(axr * k.y + axi * k.x);
}

// ============ adj_gemm: out[x][y] += sum_m W[x][m]*conjAy[m][y] ============
__global__ __launch_bounds__(256) void adj_gemm(
    const unsigned short* __restrict__ W_r, const unsigned short* __restrict__ W_i,
    const unsigned short* __restrict__ AyT_r, const unsigned short* __restrict__ AyT_i,
    float2* __restrict__ out, int kbeg, int first)
{
    __shared__ __align__(16) unsigned short Ar[64][40], Ai[64][40];
    __shared__ __align__(16) unsigned short Br[64][40], Bi[64][40];

    const int tid = threadIdx.x;
    const int x0 = blockIdx.x * 64, y0 = blockIdx.y * 64, bc = blockIdx.z;

    float4_t accR[2][2], accI[2][2];
    #pragma unroll
    for (int i = 0; i < 2; ++i)
        #pragma unroll
        for (int j = 0; j < 2; ++j) { accR[i][j] = (float4_t)0.f; accI[i][j] = (float4_t)0.f; }

    const int lane = tid & 63, wid = tid >> 6;
    const int wx = wid >> 1, wyy = wid & 1;
    const int ar = lane & 15, kb = lane >> 4;
    const int srow = tid >> 2, skg = tid & 3;

    for (int mk = 0; mk < CHUNK; mk += 32) {
        {
            size_t o = ((size_t)bc * NN + (x0 + srow)) * CHUNK + mk + skg * 8;
            *(short8_t*)&Ar[srow][skg * 8] = *(const short8_t*)(W_r + o);
            *(short8_t*)&Ai[srow][skg * 8] = *(const short8_t*)(W_i + o);
            size_t ob = (size_t)(y0 + srow) * MSTR + kbeg + mk + skg * 8;
            *(short8_t*)&Br[srow][skg * 8] = *(const short8_t*)(AyT_r + ob);
            *(short8_t*)&Bi[srow][skg * 8] = *(const short8_t*)(AyT_i + ob);
        }
        __syncthreads();

        short8_t a_r[2], a_i[2], b_r[2], b_i[2], b_n[2];
        #pragma unroll
        for (int ix = 0; ix < 2; ++ix) {
            int r = wx * 32 + ix * 16 + ar;
            a_r[ix] = *(const short8_t*)&Ar[r][kb * 8];
            a_i[ix] = *(const short8_t*)&Ai[r][kb * 8];
        }
        #pragma unroll
        for (int jy = 0; jy < 2; ++jy) {
            int c = wyy * 32 + jy * 16 + ar;
            b_r[jy] = *(const short8_t*)&Br[c][kb * 8];
            b_i[jy] = *(const short8_t*)&Bi[c][kb * 8];
            b_n[jy] = neg8(b_i[jy]);
        }
        #pragma unroll
        for (int ix = 0; ix < 2; ++ix)
            #pragma unroll
            for (int jy = 0; jy < 2; ++jy) {
                accR[ix][jy] = __builtin_amdgcn_mfma_f32_16x16x32_bf16(a_r[ix], b_r[jy], accR[ix][jy], 0, 0, 0);
                accR[ix][jy] = __builtin_amdgcn_mfma_f32_16x16x32_bf16(a_i[ix], b_n[jy], accR[ix][jy], 0, 0, 0);
                accI[ix][jy] = __builtin_amdgcn_mfma_f32_16x16x32_bf16(a_r[ix], b_i[jy], accI[ix][jy], 0, 0, 0);
                accI[ix][jy] = __builtin_amdgcn_mfma_f32_16x16x32_bf16(a_i[ix], b_r[jy], accI[ix][jy], 0, 0, 0);
            }
        __syncthreads();
    }

    #pragma unroll
    for (int ix = 0; ix < 2; ++ix)
        #pragma unroll
        for (int jy = 0; jy < 2; ++jy)
            #pragma unroll
            for (int q = 0; q < 4; ++q) {
                int x = x0 + wx * 32 + ix * 16 + kb * 4 + q;
                int y = y0 + wyy * 32 + jy * 16 + ar;
                size_t o = ((size_t)bc * NN + x) * NN + y;
                float2 v = make_float2(accR[ix][jy][q], accI[ix][jy][q]);
                if (!first) { float2 p = out[o]; v.x += p.x; v.y += p.y; }
                out[o] = v;
            }
}

// ============ host ============
extern "C" void kernel_launch(void* const* d_in, const int* in_sizes, int n_in,
                              void* d_out, int out_size, void* d_ws, size_t ws_size,
                              hipStream_t stream)
{
    const float* inp  = (const float*)d_in[0];
    const float* traj = (const float*)d_in[1];

    char* ws = (char*)d_ws;
    const size_t TPL = (size_t)NN * MSTR * 2;       // 3,932,160 B per bf16 T-plane
    unsigned short* AxT_r = (unsigned short*)(ws);
    unsigned short* AxT_i = (unsigned short*)(ws + TPL);
    unsigned short* AyT_r = (unsigned short*)(ws + 2 * TPL);
    unsigned short* AyT_i = (unsigned short*)(ws + 3 * TPL);
    float2* ksp = (float2*)(ws + 4 * TPL);
    char* rb = ws + 4 * TPL + (size_t)BCC * MSTR * 8;
    // region B, GEMM1 phase:
    unsigned short* Ax_r = (unsigned short*)(rb);
    unsigned short* Ax_i = (unsigned short*)(rb + TPL);
    unsigned short* iT_r = (unsigned short*)(rb + 2 * TPL);
    unsigned short* iT_i = (unsigned short*)(rb + 2 * TPL + (size_t)BCC * NN * NN * 2);
    float2* partial1 = (float2*)(rb + 2 * TPL + 2 * (size_t)BCC * NN * NN * 2);
    // region B, adjoint phase (aliases the above):
    unsigned short* W_r = (unsigned short*)(rb);
    unsigned short* W_i = (unsigned short*)(rb + (size_t)BCC * NN * CHUNK * 2);

    gen_A<<<dim3(96, 5), 256, 0, stream>>>(traj, Ax_r, Ax_i, AxT_r, AxT_i, AyT_r, AyT_i);
    conv_img<<<dim3(5, 5, BCC), 256, 0, stream>>>(inp, iT_r, iT_i);
    fwd_gemm<<<dim3(MT1, 5, BCC), 256, 0, stream>>>(iT_r, iT_i, Ax_r, Ax_i, AyT_r, AyT_i, partial1);
    reduce_ksp<<<dim3(24, BCC), 256, 0, stream>>>(partial1, ksp);

    for (int c = 0; c < NCHUNK; ++c) {
        int kbeg = c * CHUNK;
        gen_W<<<dim3(CHUNK / 256, NN, BCC), 256, 0, stream>>>(AxT_r, AxT_i, ksp, W_r, W_i, kbeg);
        adj_gemm<<<dim3(5, 5, BCC), 256, 0, stream>>>(W_r, W_i, AyT_r, AyT_i,
                                                      (float2*)d_out, kbeg, c == 0);
    }
}

// Round 3
// 265.260 us; speedup vs baseline: 9.9754x; 1.1225x over previous
//
#include <hip/hip_runtime.h>
#include <math.h>

// NUFFT roundtrip on bf16 MFMA (16x16x32), fp32 accumulate.
// fwd:  D[y][m] = sum_x imgT[y][x] * Ax[m][x];  ksp[m] = sum_y D[y][m]*Ay[m][y] (fused epi)
// adj:  out[x][y] = sum_m conjAx[x][m] * (ksp[m]*conjAy[m][y])  -- ksp folded into B staging,
//       split-K over m (SKADJ chunks) with fp32-or-bf16 partials chosen by ws_size.

#define NN      320
#define BCC     8
#define MREAL   6008
#define MSTR    6144          // padded m stride, 96*64
#define MT1     47            // fwd m-tiles of 128 -> 6016 cols
#define P1STR   6016
#define SKADJ   4
#define CHUNKM  (MSTR / SKADJ)   // 1536
#define TWOPI   6.283185307179586f

typedef __attribute__((ext_vector_type(8))) short short8_t;
typedef __attribute__((ext_vector_type(4))) float float4_t;

__device__ __forceinline__ unsigned short f2bf(float f) {
    union { float f; unsigned u; } v; v.f = f;
    unsigned r = v.u + 0x7fff + ((v.u >> 16) & 1);
    return (unsigned short)(r >> 16);
}
__device__ __forceinline__ float bf2f(unsigned short h) {
    union { unsigned u; float f; } v; v.u = ((unsigned)h) << 16;
    return v.f;
}
__device__ __forceinline__ short8_t neg8(short8_t v) {
    short8_t r;
    #pragma unroll
    for (int i = 0; i < 8; ++i) r[i] = v[i] ^ (short)0x8000;
    return r;
}
__device__ __forceinline__ float gval(int i) { return (float)(i - NN/2); }

__device__ __forceinline__ void phase_cs(float k, float g, float* c, float* s) {
    float rev = k * (g * (1.0f / (float)NN));
    rev -= rintf(rev);
    float th = rev * TWOPI;
    __sincosf(th, s, c);
}

// ============ gen_A: build Ax[m][x], AxTc[x][m], AyT[y][m] ============
__global__ __launch_bounds__(256) void gen_A(
    const float* __restrict__ traj,
    unsigned short* __restrict__ Ax_r, unsigned short* __restrict__ Ax_i,
    unsigned short* __restrict__ AxT_r, unsigned short* __restrict__ AxT_i,
    unsigned short* __restrict__ AyT_r, unsigned short* __restrict__ AyT_i)
{
    __shared__ __align__(16) float lc[64][65];
    __shared__ __align__(16) float ls[64][65];
    __shared__ float kxv[64], kyv[64];
    const int tid = threadIdx.x;
    const int m0 = blockIdx.x * 64;
    const int g0 = blockIdx.y * 64;

    if (tid < 64) {
        int m = m0 + tid;
        kxv[tid] = (m < MREAL) ? traj[2*m]     : 0.f;
        kyv[tid] = (m < MREAL) ? traj[2*m + 1] : 0.f;
    }
    __syncthreads();

    #pragma unroll
    for (int it = 0; it < 16; ++it) {
        int e = tid + it * 256;
        int mi = e >> 6, gi = e & 63;
        float c, s;
        phase_cs(kxv[mi], gval(g0 + gi), &c, &s);
        bool valid = (m0 + mi) < MREAL;
        lc[mi][gi] = valid ? c : 0.f;
        ls[mi][gi] = valid ? s : 0.f;
    }
    __syncthreads();
    #pragma unroll
    for (int it = 0; it < 16; ++it) {       // Ax[m][x] = (c, -s)
        int e = tid + it * 256;
        int mi = e >> 6, xi = e & 63;
        size_t o = (size_t)(m0 + mi) * NN + (g0 + xi);
        Ax_r[o] = f2bf(lc[mi][xi]);
        Ax_i[o] = f2bf(-ls[mi][xi]);
    }
    #pragma unroll
    for (int it = 0; it < 16; ++it) {       // AxTc[x][m] = (c, +s)
        int e = tid + it * 256;
        int xi = e >> 6, mi = e & 63;
        size_t o = (size_t)(g0 + xi) * MSTR + (m0 + mi);
        AxT_r[o] = f2bf(lc[mi][xi]);
        AxT_i[o] = f2bf(ls[mi][xi]);
    }
    __syncthreads();

    #pragma unroll
    for (int it = 0; it < 16; ++it) {
        int e = tid + it * 256;
        int mi = e >> 6, gi = e & 63;
        float c, s;
        phase_cs(kyv[mi], gval(g0 + gi), &c, &s);
        bool valid = (m0 + mi) < MREAL;
        lc[mi][gi] = valid ? c : 0.f;
        ls[mi][gi] = valid ? s : 0.f;
    }
    __syncthreads();
    #pragma unroll
    for (int it = 0; it < 16; ++it) {       // AyT[y][m] = (c, +s) = conj(Ay)
        int e = tid + it * 256;
        int yi = e >> 6, mi = e & 63;
        size_t o = (size_t)(g0 + yi) * MSTR + (m0 + mi);
        AyT_r[o] = f2bf(lc[mi][yi]);
        AyT_i[o] = f2bf(ls[mi][yi]);
    }
}

// ============ conv_img: inp float2 [bc][x][y] -> imgT bf16 [bc][y][x] ============
__global__ __launch_bounds__(256) void conv_img(
    const float* __restrict__ inp,
    unsigned short* __restrict__ iT_r, unsigned short* __restrict__ iT_i)
{
    __shared__ __align__(16) float2 t[64][65];
    const int tid = threadIdx.x;
    const int x0 = blockIdx.x * 64, y0 = blockIdx.y * 64, bc = blockIdx.z;
    const float2* ip = (const float2*)inp;
    #pragma unroll
    for (int it = 0; it < 16; ++it) {
        int e = tid + it * 256;
        int r = e >> 6, c = e & 63;
        t[r][c] = ip[((size_t)bc * NN + (x0 + r)) * NN + (y0 + c)];
    }
    __syncthreads();
    #pragma unroll
    for (int it = 0; it < 16; ++it) {
        int e = tid + it * 256;
        int yy = e >> 6, xx = e & 63;
        float2 v = t[xx][yy];
        size_t o = ((size_t)bc * NN + (y0 + yy)) * NN + (x0 + xx);
        iT_r[o] = f2bf(v.x);
        iT_i[o] = f2bf(v.y);
    }
}

// ============ fwd_gemm: 64y x 128m tile, BK=64, fused Ay-reduce, XCD swizzle ============
__global__ __launch_bounds__(256) void fwd_gemm(
    const unsigned short* __restrict__ iT_r, const unsigned short* __restrict__ iT_i,
    const unsigned short* __restrict__ Ax_r, const unsigned short* __restrict__ Ax_i,
    const unsigned short* __restrict__ AyT_r, const unsigned short* __restrict__ AyT_i,
    float2* __restrict__ partial1)
{
    __shared__ __align__(16) unsigned short Ar[64][72],  Ai[64][72];
    __shared__ __align__(16) unsigned short Br[128][72], Bi[128][72];
    __shared__ __align__(16) float2 redbuf[2][128];

    const int tid = threadIdx.x;
    // grid = 1880 = 47 mt * 5 yt * 8 bc ; XCD-chunked: same mt contiguous per XCD
    const int bid = blockIdx.x;
    const int nid = (bid & 7) * 235 + (bid >> 3);
    const int mt  = nid / 40;
    const int r40 = nid - mt * 40;
    const int yt  = r40 % 5;
    const int bc  = r40 / 5;
    const int m0  = mt * 128;
    const int y0  = yt * 64;

    float4_t accR[2][4], accI[2][4];
    #pragma unroll
    for (int i = 0; i < 2; ++i)
        #pragma unroll
        for (int j = 0; j < 4; ++j) { accR[i][j] = (float4_t)0.f; accI[i][j] = (float4_t)0.f; }

    const int lane = tid & 63, wid = tid >> 6;
    const int wy = wid & 1, wm = wid >> 1;
    const int ar = lane & 15, kb = lane >> 4;

    for (int x0 = 0; x0 < NN; x0 += 64) {
        // stage A (imgT): 64 rows x 64 elems, 2 planes
        #pragma unroll
        for (int it = 0; it < 2; ++it) {
            int e = tid + it * 256;
            int row = e >> 3, gr = e & 7;
            size_t o = ((size_t)bc * NN + (y0 + row)) * NN + x0 + gr * 8;
            *(short8_t*)&Ar[row][gr * 8] = *(const short8_t*)(iT_r + o);
            *(short8_t*)&Ai[row][gr * 8] = *(const short8_t*)(iT_i + o);
        }
        // stage B (Ax): 128 rows x 64 elems, 2 planes
        #pragma unroll
        for (int it = 0; it < 4; ++it) {
            int e = tid + it * 256;
            int row = e >> 3, gr = e & 7;
            size_t o = (size_t)(m0 + row) * NN + x0 + gr * 8;
            *(short8_t*)&Br[row][gr * 8] = *(const short8_t*)(Ax_r + o);
            *(short8_t*)&Bi[row][gr * 8] = *(const short8_t*)(Ax_i + o);
        }
        __syncthreads();

        #pragma unroll
        for (int ks = 0; ks < 2; ++ks) {
            short8_t a_r[2], a_i[2], a_n[2], b_r[4], b_i[4];
            #pragma unroll
            for (int iy = 0; iy < 2; ++iy) {
                int rr = wy * 32 + iy * 16 + ar;
                a_r[iy] = *(const short8_t*)&Ar[rr][ks * 32 + kb * 8];
                a_i[iy] = *(const short8_t*)&Ai[rr][ks * 32 + kb * 8];
                a_n[iy] = neg8(a_i[iy]);
            }
            #pragma unroll
            for (int jm = 0; jm < 4; ++jm) {
                int cc = wm * 64 + jm * 16 + ar;
                b_r[jm] = *(const short8_t*)&Br[cc][ks * 32 + kb * 8];
                b_i[jm] = *(const short8_t*)&Bi[cc][ks * 32 + kb * 8];
            }
            #pragma unroll
            for (int iy = 0; iy < 2; ++iy)
                #pragma unroll
                for (int jm = 0; jm < 4; ++jm) {
                    accR[iy][jm] = __builtin_amdgcn_mfma_f32_16x16x32_bf16(a_r[iy], b_r[jm], accR[iy][jm], 0, 0, 0);
                    accR[iy][jm] = __builtin_amdgcn_mfma_f32_16x16x32_bf16(a_n[iy], b_i[jm], accR[iy][jm], 0, 0, 0);
                    accI[iy][jm] = __builtin_amdgcn_mfma_f32_16x16x32_bf16(a_r[iy], b_i[jm], accI[iy][jm], 0, 0, 0);
                    accI[iy][jm] = __builtin_amdgcn_mfma_f32_16x16x32_bf16(a_i[iy], b_r[jm], accI[iy][jm], 0, 0, 0);
                }
        }
        __syncthreads();
    }

    // epilogue: ksp partial = sum_y D[y][m]*Ay[m][y]; AyT stores (c,+s), Ay=(c,-s)
    #pragma unroll
    for (int jm = 0; jm < 4; ++jm) {
        float sr = 0.f, si = 0.f;
        int m = m0 + wm * 64 + jm * 16 + ar;
        #pragma unroll
        for (int iy = 0; iy < 2; ++iy)
            #pragma unroll
            for (int q = 0; q < 4; ++q) {
                int y = y0 + wy * 32 + iy * 16 + kb * 4 + q;
                float c  = bf2f(AyT_r[(size_t)y * MSTR + m]);
                float sy = bf2f(AyT_i[(size_t)y * MSTR + m]);
                float Tr = accR[iy][jm][q], Ti = accI[iy][jm][q];
                sr += Tr * c + Ti * sy;
                si += Ti * c - Tr * sy;
            }
        sr += __shfl_xor(sr, 16); sr += __shfl_xor(sr, 32);
        si += __shfl_xor(si, 16); si += __shfl_xor(si, 32);
        if ((lane & 48) == 0)
            redbuf[wy][wm * 64 + jm * 16 + ar] = make_float2(sr, si);
    }
    __syncthreads();
    if (tid < 128) {
        float2 a = redbuf[0][tid], b = redbuf[1][tid];
        int m = m0 + tid;
        if (m < MREAL)
            partial1[((size_t)bc * 5 + yt) * P1STR + m] = make_float2(a.x + b.x, a.y + b.y);
    }
}

// ============ reduce_ksp ============
__global__ void reduce_ksp(const float2* __restrict__ partial1,
                           float2* __restrict__ ksp)
{
    int mp = blockIdx.x * 256 + threadIdx.x;   // grid (24, 8)
    int bc = blockIdx.y;
    float2 r = make_float2(0.f, 0.f);
    if (mp < MREAL) {
        #pragma unroll
        for (int yt = 0; yt < 5; ++yt) {
            float2 v = partial1[((size_t)bc * 5 + yt) * P1STR + mp];
            r.x += v.x; r.y += v.y;
        }
    }
    ksp[(size_t)bc * MSTR + mp] = r;
}

// ============ adj_gemm: out-tile 64x x 64y, BK=64, split-K, ksp folded in B staging ====
template<int FP32P>
__global__ __launch_bounds__(256) void adj_gemm(
    const unsigned short* __restrict__ AxT_r, const unsigned short* __restrict__ AxT_i,
    const unsigned short* __restrict__ AyT_r, const unsigned short* __restrict__ AyT_i,
    const float2* __restrict__ ksp, void* __restrict__ partial2)
{
    __shared__ __align__(16) unsigned short Ar[64][72], Ai[64][72];
    __shared__ __align__(16) unsigned short Br[64][72], Bi[64][72];
    __shared__ __align__(16) float2 kspl[CHUNKM];

    const int tid = threadIdx.x;
    // grid = 800 = (8 bc * SKADJ) * 25 xy ; XCD-chunked: same (bc,sk) contiguous per XCD
    const int bid = blockIdx.x;
    const int nid = (bid & 7) * 100 + (bid >> 3);
    const int bcsk = nid / 25;
    const int xy = nid - bcsk * 25;
    const int xt = xy / 5, yt = xy % 5;
    const int bc = bcsk & 7, sk = bcsk >> 3;
    const int x0 = xt * 64, y0 = yt * 64;
    const int kbeg = sk * CHUNKM;

    #pragma unroll
    for (int it = 0; it < CHUNKM / 256; ++it)
        kspl[tid + it * 256] = ksp[(size_t)bc * MSTR + kbeg + tid + it * 256];
    __syncthreads();

    float4_t accR[2][2], accI[2][2];
    #pragma unroll
    for (int i = 0; i < 2; ++i)
        #pragma unroll
        for (int j = 0; j < 2; ++j) { accR[i][j] = (float4_t)0.f; accI[i][j] = (float4_t)0.f; }

    const int lane = tid & 63, wid = tid >> 6;
    const int wx = wid >> 1, wyy = wid & 1;
    const int ar = lane & 15, kb = lane >> 4;

    for (int mk = 0; mk < CHUNKM; mk += 64) {
        // stage A = conjAx (AxTc stored (c,+s)), unscaled
        #pragma unroll
        for (int it = 0; it < 2; ++it) {
            int e = tid + it * 256;
            int row = e >> 3, gr = e & 7;
            size_t o = (size_t)(x0 + row) * MSTR + kbeg + mk + gr * 8;
            *(short8_t*)&Ar[row][gr * 8] = *(const short8_t*)(AxT_r + o);
            *(short8_t*)&Ai[row][gr * 8] = *(const short8_t*)(AxT_i + o);
        }
        // stage B = ksp[m] * conjAy[m][y]  (AyT stored (c,+s) = conjAy)
        #pragma unroll
        for (int it = 0; it < 2; ++it) {
            int e = tid + it * 256;
            int row = e >> 3, gr = e & 7;
            size_t o = (size_t)(y0 + row) * MSTR + kbeg + mk + gr * 8;
            short8_t yr = *(const short8_t*)(AyT_r + o);
            short8_t yi = *(const short8_t*)(AyT_i + o);
            short8_t br, bi2;
            #pragma unroll
            for (int j = 0; j < 8; ++j) {
                float2 k = kspl[mk + gr * 8 + j];
                float cr = bf2f((unsigned short)yr[j]);
                float ci = bf2f((unsigned short)yi[j]);
                br[j]  = (short)f2bf(k.x * cr - k.y * ci);
                bi2[j] = (short)f2bf(k.x * ci + k.y * cr);
            }
            *(short8_t*)&Br[row][gr * 8] = br;
            *(short8_t*)&Bi[row][gr * 8] = bi2;
        }
        __syncthreads();

        #pragma unroll
        for (int ks = 0; ks < 2; ++ks) {
            short8_t a_r[2], a_i[2], a_n[2], b_r[2], b_i[2];
            #pragma unroll
            for (int ix = 0; ix < 2; ++ix) {
                int rr = wx * 32 + ix * 16 + ar;
                a_r[ix] = *(const short8_t*)&Ar[rr][ks * 32 + kb * 8];
                a_i[ix] = *(const short8_t*)&Ai[rr][ks * 32 + kb * 8];
                a_n[ix] = neg8(a_i[ix]);
            }
            #pragma unroll
            for (int jy = 0; jy < 2; ++jy) {
                int cc = wyy * 32 + jy * 16 + ar;
                b_r[jy] = *(const short8_t*)&Br[cc][ks * 32 + kb * 8];
                b_i[jy] = *(const short8_t*)&Bi[cc][ks * 32 + kb * 8];
            }
            #pragma unroll
            for (int ix = 0; ix < 2; ++ix)
                #pragma unroll
                for (int jy = 0; jy < 2; ++jy) {
                    accR[ix][jy] = __builtin_amdgcn_mfma_f32_16x16x32_bf16(a_r[ix], b_r[jy], accR[ix][jy], 0, 0, 0);
                    accR[ix][jy] = __builtin_amdgcn_mfma_f32_16x16x32_bf16(a_n[ix], b_i[jy], accR[ix][jy], 0, 0, 0);
                    accI[ix][jy] = __builtin_amdgcn_mfma_f32_16x16x32_bf16(a_r[ix], b_i[jy], accI[ix][jy], 0, 0, 0);
                    accI[ix][jy] = __builtin_amdgcn_mfma_f32_16x16x32_bf16(a_i[ix], b_r[jy], accI[ix][jy], 0, 0, 0);
                }
        }
        __syncthreads();
    }

    // write split-K partial
    #pragma unroll
    for (int ix = 0; ix < 2; ++ix)
        #pragma unroll
        for (int jy = 0; jy < 2; ++jy)
            #pragma unroll
            for (int q = 0; q < 4; ++q) {
                int x = x0 + wx * 32 + ix * 16 + kb * 4 + q;
                int y = y0 + wyy * 32 + jy * 16 + ar;
                size_t o = (((size_t)sk * BCC + bc) * NN + x) * NN + y;
                float vr = accR[ix][jy][q], vi = accI[ix][jy][q];
                if (FP32P) {
                    ((float2*)partial2)[o] = make_float2(vr, vi);
                } else {
                    ((unsigned*)partial2)[o] =
                        (unsigned)f2bf(vr) | ((unsigned)f2bf(vi) << 16);
                }
            }
}

// ============ reduce_out ============
template<int FP32P>
__global__ void reduce_out(const void* __restrict__ partial2,
                           float2* __restrict__ out)
{
    size_t total = (size_t)BCC * NN * NN;
    size_t idx = (size_t)blockIdx.x * 256 + threadIdx.x;
    if (idx >= total) return;
    float2 r = make_float2(0.f, 0.f);
    #pragma unroll
    for (int s = 0; s < SKADJ; ++s) {
        if (FP32P) {
            float2 v = ((const float2*)partial2)[s * total + idx];
            r.x += v.x; r.y += v.y;
        } else {
            unsigned u = ((const unsigned*)partial2)[s * total + idx];
            r.x += bf2f((unsigned short)(u & 0xffff));
            r.y += bf2f((unsigned short)(u >> 16));
        }
    }
    out[idx] = r;
}

// ============ host ============
extern "C" void kernel_launch(void* const* d_in, const int* in_sizes, int n_in,
                              void* d_out, int out_size, void* d_ws, size_t ws_size,
                              hipStream_t stream)
{
    const float* inp  = (const float*)d_in[0];
    const float* traj = (const float*)d_in[1];

    char* ws = (char*)d_ws;
    const size_t PL = (size_t)NN * MSTR * 2;           // 3,932,160 B per bf16 plane
    unsigned short* AxT_r = (unsigned short*)(ws);
    unsigned short* AxT_i = (unsigned short*)(ws + PL);
    unsigned short* AyT_r = (unsigned short*)(ws + 2 * PL);
    unsigned short* AyT_i = (unsigned short*)(ws + 3 * PL);
    float2* ksp = (float2*)(ws + 4 * PL);
    const size_t KSPB = (size_t)BCC * MSTR * 8;        // 393,216
    char* rb = ws + 4 * PL + KSPB;                     // region B @ 16,121,856
    // fwd phase (dead after reduce_ksp):
    unsigned short* Ax_r = (unsigned short*)(rb);
    unsigned short* Ax_i = (unsigned short*)(rb + PL);
    const size_t ITP = (size_t)BCC * NN * NN * 2;      // 1,638,400 per plane
    unsigned short* iT_r = (unsigned short*)(rb + 2 * PL);
    unsigned short* iT_i = (unsigned short*)(rb + 2 * PL + ITP);
    float2* partial1 = (float2*)(rb + 2 * PL + 2 * ITP);
    // adj phase (aliases fwd region):
    void* partial2 = (void*)rb;
    const size_t ADJ_F32 = (size_t)SKADJ * BCC * NN * NN * 8;   // 26,214,400
    const size_t BASE = 4 * PL + KSPB;
    const int fp32p = (ws_size >= BASE + ADJ_F32) ? 1 : 0;

    gen_A<<<dim3(96, 5), 256, 0, stream>>>(traj, Ax_r, Ax_i, AxT_r, AxT_i, AyT_r, AyT_i);
    conv_img<<<dim3(5, 5, BCC), 256, 0, stream>>>(inp, iT_r, iT_i);
    fwd_gemm<<<dim3(1880), 256, 0, stream>>>(iT_r, iT_i, Ax_r, Ax_i, AyT_r, AyT_i, partial1);
    reduce_ksp<<<dim3(24, BCC), 256, 0, stream>>>(partial1, ksp);

    size_t total = (size_t)BCC * NN * NN;
    int rblocks = (int)((total + 255) / 256);
    if (fp32p) {
        adj_gemm<1><<<dim3(800), 256, 0, stream>>>(AxT_r, AxT_i, AyT_r, AyT_i, ksp, partial2);
        reduce_out<1><<<rblocks, 256, 0, stream>>>(partial2, (float2*)d_out);
    } else {
        adj_gemm<0><<<dim3(800), 256, 0, stream>>>(AxT_r, AxT_i, AyT_r, AyT_i, ksp, partial2);
        reduce_out<0><<<rblocks, 256, 0, stream>>>(partial2, (float2*)d_out);
    }
}